// Round 1
// baseline (3320.264 us; speedup 1.0000x reference)
//
#include <hip/hip_runtime.h>

// Problem constants (fixed by the reference)
constexpr int Nn = 16384;   // nodes at current level
constexpr int Mm = 8192;    // nodes at coarser level (K of big GEMM)
constexpr int Ee = 524288;  // edges
constexpr int Dd = 128;     // feature dim

// ---------------------------------------------------------------------------
// Degree kernels: deg starts at 1.0 (self-loop), +1 per incident edge, then
// converted in-place to rsqrt(deg).
// ---------------------------------------------------------------------------
__global__ void k_deg_init(float* __restrict__ deg) {
    int i = blockIdx.x * 256 + threadIdx.x;
    if (i < 2 * Nn) deg[i] = 1.0f;
}

__global__ void k_deg_count(const int* __restrict__ src, const int* __restrict__ dst,
                            float* __restrict__ rs_out, float* __restrict__ rs_in) {
    int e = blockIdx.x * 256 + threadIdx.x;
    if (e < Ee) {
        atomicAdd(&rs_out[src[e]], 1.0f);
        atomicAdd(&rs_in[dst[e]], 1.0f);
    }
}

__global__ void k_deg_rsqrt(float* __restrict__ deg) {
    int i = blockIdx.x * 256 + threadIdx.x;
    if (i < 2 * Nn) deg[i] = rsqrtf(deg[i]);
}

__global__ void k_zero(float4* __restrict__ p, int n4) {
    int i = blockIdx.x * 256 + threadIdx.x;
    if (i < n4) p[i] = float4{0.f, 0.f, 0.f, 0.f};
}

// ---------------------------------------------------------------------------
// Tiled f32 GEMM: C[Nn, 128] = A[Nn, K] @ B[K, 128], K multiple of 32.
// 32 rows x 128 cols per block of 256 threads; Bk = 32. Grid = Nn/32 = 512
// blocks -> 2 blocks/CU. Per thread: 4 rows x 4 cols accumulators.
// A is read exactly once from HBM; B (<=4 MB) streams from L2/L3.
// Epilogue modes: 0 = plain store (big GEMM)
//                 1 = out = (acc + bias) * scale          (conv path)
//                 2 = out = ((acc+bias)*scale + prev)*0.5 (top-down + combine)
// ---------------------------------------------------------------------------
__launch_bounds__(256, 2)
__global__ void k_gemm(const float* __restrict__ A, const float* __restrict__ B,
                       float* __restrict__ C, int K,
                       const float* __restrict__ bias, const float* __restrict__ scale,
                       const float* __restrict__ prev, int mode) {
    __shared__ float As[32 * 36];    // [kk][row], row-dim padded 32->36 (16B-aligned rows)
    __shared__ float Bs[32 * 128];   // [kk][col]

    const int tid = threadIdx.x;
    const int tx = tid & 31;         // col group
    const int ty = tid >> 5;         // row group (0..7)
    const int c4 = tx * 4;
    const int r0 = ty * 4;
    const int row0 = blockIdx.x * 32;

    // A staging map: each thread loads one float4: row ar, cols ak..ak+3
    const int ar = tid >> 3;         // 0..31
    const int ak = (tid & 7) * 4;    // 0,4,..,28
    const float* Arow = A + (size_t)(row0 + ar) * K + ak;

    float acc[4][4] = {};

    for (int k0 = 0; k0 < K; k0 += 32) {
        // global loads for this tile (issued before the barrier)
        float4 av = *(const float4*)(Arow + k0);
        float4 bv[4];
#pragma unroll
        for (int t = 0; t < 4; t++) {
            int idx = tid + t * 256;             // 0..1023
            int br = idx >> 5, bc = (idx & 31) * 4;
            bv[t] = *(const float4*)(B + (size_t)(k0 + br) * 128 + bc);
        }
        __syncthreads();  // previous iteration's LDS reads complete
        As[(ak + 0) * 36 + ar] = av.x;
        As[(ak + 1) * 36 + ar] = av.y;
        As[(ak + 2) * 36 + ar] = av.z;
        As[(ak + 3) * 36 + ar] = av.w;
#pragma unroll
        for (int t = 0; t < 4; t++) {
            int idx = tid + t * 256;
            int br = idx >> 5, bc = (idx & 31) * 4;
            *(float4*)(Bs + br * 128 + bc) = bv[t];
        }
        __syncthreads();
#pragma unroll
        for (int kk = 0; kk < 32; kk++) {
            float4 a4 = *(const float4*)(As + kk * 36 + r0);
            float4 b4 = *(const float4*)(Bs + kk * 128 + c4);
            float a[4] = {a4.x, a4.y, a4.z, a4.w};
            float b[4] = {b4.x, b4.y, b4.z, b4.w};
#pragma unroll
            for (int i = 0; i < 4; i++)
#pragma unroll
                for (int j = 0; j < 4; j++)
                    acc[i][j] = fmaf(a[i], b[j], acc[i][j]);
        }
    }

    float4 bi = {0.f, 0.f, 0.f, 0.f}, sc = {1.f, 1.f, 1.f, 1.f};
    if (mode >= 1) {
        bi = *(const float4*)(bias + c4);
        sc = *(const float4*)(scale + c4);
    }
#pragma unroll
    for (int i = 0; i < 4; i++) {
        size_t o = (size_t)(row0 + r0 + i) * 128 + c4;
        float4 v = {acc[i][0], acc[i][1], acc[i][2], acc[i][3]};
        if (mode >= 1) {
            v.x = (v.x + bi.x) * sc.x;
            v.y = (v.y + bi.y) * sc.y;
            v.z = (v.z + bi.z) * sc.z;
            v.w = (v.w + bi.w) * sc.w;
        }
        if (mode == 2) {
            float4 p = *(const float4*)(prev + o);
            v.x = (v.x + p.x) * 0.5f;
            v.y = (v.y + p.y) * 0.5f;
            v.z = (v.z + p.z) * 0.5f;
            v.w = (v.w + p.w) * 0.5f;
        }
        *(float4*)(C + o) = v;
    }
}

// ---------------------------------------------------------------------------
// SpMM scatter: agg[dst] += x[src] * rs_out[src], 32 threads per edge
// (4 features each, float4 gather, 4 scalar f32 atomics).
// ---------------------------------------------------------------------------
__global__ void k_scatter(const float* __restrict__ x, const float* __restrict__ rs_out,
                          const int* __restrict__ src, const int* __restrict__ dst,
                          float* __restrict__ agg) {
    int idx = blockIdx.x * 256 + threadIdx.x;   // Ee*32 total, grid exact
    int e = idx >> 5;
    int c4 = (idx & 31) * 4;
    int s = src[e], d = dst[e];
    float rs = rs_out[s];
    float4 v = *(const float4*)(x + (size_t)s * 128 + c4);
    float* o = agg + (size_t)d * 128 + c4;
    atomicAdd(o + 0, v.x * rs);
    atomicAdd(o + 1, v.y * rs);
    atomicAdd(o + 2, v.z * rs);
    atomicAdd(o + 3, v.w * rs);
}

// agg = (agg + x * rs_out[row]) * rs_in[row]   (self-loop + in-degree norm)
__global__ void k_finalize(float* __restrict__ agg, const float* __restrict__ x,
                           const float* __restrict__ rs_out, const float* __restrict__ rs_in) {
    int idx = blockIdx.x * 256 + threadIdx.x;   // Nn*32 total, grid exact
    int row = idx >> 5;
    int c4 = (idx & 31) * 4;
    float ro = rs_out[row], ri = rs_in[row];
    size_t o = (size_t)row * 128 + c4;
    float4 a = *(const float4*)(agg + o);
    float4 v = *(const float4*)(x + o);
    a.x = (a.x + v.x * ro) * ri;
    a.y = (a.y + v.y * ro) * ri;
    a.z = (a.z + v.z * ro) * ri;
    a.w = (a.w + v.w * ro) * ri;
    *(float4*)(agg + o) = a;
}

// ---------------------------------------------------------------------------
// LayerNorm (feature dim 128) + affine + ReLU. One wave per row, float2/lane.
// ---------------------------------------------------------------------------
__global__ void k_ln_relu(const float* __restrict__ x, const float* __restrict__ gamma,
                          const float* __restrict__ beta, float* __restrict__ out) {
    int wave = threadIdx.x >> 6;   // 0..3
    int lane = threadIdx.x & 63;
    int row = blockIdx.x * 4 + wave;
    const float* xr = x + (size_t)row * 128;
    float2 v = *(const float2*)(xr + lane * 2);
    float s1 = v.x + v.y;
    float s2 = v.x * v.x + v.y * v.y;
#pragma unroll
    for (int m = 32; m >= 1; m >>= 1) {
        s1 += __shfl_xor(s1, m);
        s2 += __shfl_xor(s2, m);
    }
    float mu = s1 * (1.0f / 128.0f);
    float var = s2 * (1.0f / 128.0f) - mu * mu;
    float inv = rsqrtf(var + 1e-5f);
    float2 g = *(const float2*)(gamma + lane * 2);
    float2 b = *(const float2*)(beta + lane * 2);
    float2 o;
    o.x = fmaxf((v.x - mu) * inv * g.x + b.x, 0.0f);
    o.y = fmaxf((v.y - mu) * inv * g.y + b.y, 0.0f);
    *(float2*)(out + (size_t)row * 128 + lane * 2) = o;
}

// ---------------------------------------------------------------------------
extern "C" void kernel_launch(void* const* d_in, const int* in_sizes, int n_in,
                              void* d_out, int out_size, void* d_ws, size_t ws_size,
                              hipStream_t stream) {
    const float* curr_h    = (const float*)d_in[0];
    const float* next_h    = (const float*)d_in[1];
    const float* curr_inc  = (const float*)d_in[2];
    const float* Wc        = (const float*)d_in[3];
    const float* bc        = (const float*)d_in[4];
    const float* Wf        = (const float*)d_in[5];
    const float* bf        = (const float*)d_in[6];
    const float* conv_w    = (const float*)d_in[7];
    const float* topDown_w = (const float*)d_in[8];
    const float* gamma     = (const float*)d_in[9];
    const float* beta      = (const float*)d_in[10];
    const int*   esrc      = (const int*)d_in[11];
    const int*   edst      = (const int*)d_in[12];
    float* out = (float*)d_out;

    // workspace layout (floats): rs_out[N] | rs_in[N] | agg[N*D] | path[N*D] | fused[N*D]
    // total = 2*16384 + 3*2097152 floats = ~25.3 MB
    float* ws     = (float*)d_ws;
    float* rs_out = ws;
    float* rs_in  = ws + Nn;
    float* agg    = ws + 2 * Nn;
    float* path   = agg + (size_t)Nn * Dd;
    float* fused  = path + (size_t)Nn * Dd;

    const int nd4 = Nn * Dd / 4;

    // degrees -> rsqrt
    k_deg_init<<<(2 * Nn) / 256, 256, 0, stream>>>(rs_out);
    k_deg_count<<<Ee / 256, 256, 0, stream>>>(esrc, edst, rs_out, rs_in);
    k_deg_rsqrt<<<(2 * Nn) / 256, 256, 0, stream>>>(rs_out);

    // fused_in = curr_inc @ next_h   (the big one: K = 8192)
    k_gemm<<<Nn / 32, 256, 0, stream>>>(curr_inc, next_h, fused, Mm,
                                        nullptr, nullptr, nullptr, 0);

    // conv path: graph_conv(curr_h) @ Wc, * conv_w
    k_zero<<<nd4 / 256, 256, 0, stream>>>((float4*)agg, nd4);
    k_scatter<<<(Ee * 32) / 256, 256, 0, stream>>>(curr_h, rs_out, esrc, edst, agg);
    k_finalize<<<(Nn * 32) / 256, 256, 0, stream>>>(agg, curr_h, rs_out, rs_in);
    k_gemm<<<Nn / 32, 256, 0, stream>>>(agg, Wc, path, Dd, bc, conv_w, nullptr, 1);

    // top-down path: graph_conv(fused) @ Wf, * topDown_w; combine with conv path
    k_zero<<<nd4 / 256, 256, 0, stream>>>((float4*)agg, nd4);
    k_scatter<<<(Ee * 32) / 256, 256, 0, stream>>>(fused, rs_out, esrc, edst, agg);
    k_finalize<<<(Nn * 32) / 256, 256, 0, stream>>>(agg, fused, rs_out, rs_in);
    k_gemm<<<Nn / 32, 256, 0, stream>>>(agg, Wf, path, Dd, bf, topDown_w, path, 2);

    // LayerNorm + ReLU -> out
    k_ln_relu<<<Nn / 4, 256, 0, stream>>>(path, gamma, beta, out);
}

// Round 2
// 998.887 us; speedup vs baseline: 3.3240x; 3.3240x over previous
//
#include <hip/hip_runtime.h>

// Problem constants (fixed by the reference)
constexpr int Nn = 16384;   // nodes at current level
constexpr int Mm = 8192;    // K of big GEMM
constexpr int Ee = 524288;  // edges
constexpr int Dd = 128;     // feature dim

typedef __attribute__((ext_vector_type(8))) short short8v;
typedef __attribute__((ext_vector_type(4))) short short4v;
typedef __attribute__((ext_vector_type(4))) float float4v;

// f32 -> bf16 round-to-nearest-even (inputs finite; no NaN handling needed)
static __device__ __forceinline__ short f2bf(float f) {
    unsigned u = __builtin_bit_cast(unsigned, f);
    u += 0x7fffu + ((u >> 16) & 1u);
    return (short)(u >> 16);
}

// ---------------------------------------------------------------------------
// CSR build + degrees
// ---------------------------------------------------------------------------
__global__ void k_zero_i(int* __restrict__ p, int n) {
    int i = blockIdx.x * 256 + threadIdx.x;
    if (i < n) p[i] = 0;
}

__global__ void k_deg_count(const int* __restrict__ src, const int* __restrict__ dst,
                            int* __restrict__ cnt_out, int* __restrict__ cnt_in) {
    int e = blockIdx.x * 256 + threadIdx.x;
    if (e < Ee) {
        atomicAdd(&cnt_out[src[e]], 1);
        atomicAdd(&cnt_in[dst[e]], 1);
    }
}

__global__ void k_deg_fin(const int* __restrict__ cnt_out, const int* __restrict__ cnt_in,
                          float* __restrict__ rs_out, float* __restrict__ rs_in) {
    int i = blockIdx.x * 256 + threadIdx.x;
    if (i < Nn) {
        rs_out[i] = rsqrtf((float)(cnt_out[i] + 1));   // +1 self-loop
        rs_in[i]  = rsqrtf((float)(cnt_in[i] + 1));
    }
}

// Exclusive prefix sum of cnt[16384] -> row_start[16385]. One block, 1024 thr.
__global__ void k_scan(const int* __restrict__ cnt, int* __restrict__ row_start) {
    __shared__ int s[1024];
    int t = threadIdx.x;
    int base = t * 16;
    int local[16];
    int sum = 0;
#pragma unroll
    for (int i = 0; i < 16; i++) { local[i] = cnt[base + i]; sum += local[i]; }
    s[t] = sum;
    __syncthreads();
    for (int off = 1; off < 1024; off <<= 1) {
        int v = (t >= off) ? s[t - off] : 0;
        __syncthreads();
        s[t] += v;
        __syncthreads();
    }
    int run = s[t] - sum;   // exclusive offset for this thread's chunk
#pragma unroll
    for (int i = 0; i < 16; i++) { row_start[base + i] = run; run += local[i]; }
    if (t == 1023) row_start[16384] = s[1023];
}

__global__ void k_fill(const int* __restrict__ src, const int* __restrict__ dst,
                       const int* __restrict__ row_start, int* __restrict__ cursor,
                       int* __restrict__ ebuf) {
    int e = blockIdx.x * 256 + threadIdx.x;
    if (e < Ee) {
        int d = dst[e];
        int pos = atomicAdd(&cursor[d], 1);
        ebuf[row_start[d] + pos] = src[e];
    }
}

// ---------------------------------------------------------------------------
// Gather-only graph-conv aggregation, finalize fused.
// One wave per dst node; lane handles 2 features (float2).
// agg[d] = (sum_{e: dst=d} x[src_e]*rs_out[src_e] + x[d]*rs_out[d]) * rs_in[d]
// ---------------------------------------------------------------------------
__global__ void k_agg(const float* __restrict__ x, const float* __restrict__ rs_o,
                      const float* __restrict__ rs_i, const int* __restrict__ row_start,
                      const int* __restrict__ ebuf, float* __restrict__ agg) {
    int d = blockIdx.x * 4 + (threadIdx.x >> 6);
    int lane = threadIdx.x & 63;
    int c = lane * 2;
    int beg = row_start[d], end = row_start[d + 1];
    float ax = 0.f, ay = 0.f;
    int i = beg;
    for (; i + 1 < end; i += 2) {   // unroll 2 for load ILP
        int s0 = ebuf[i], s1 = ebuf[i + 1];
        float r0 = rs_o[s0], r1 = rs_o[s1];
        float2 v0 = *(const float2*)(x + (size_t)s0 * 128 + c);
        float2 v1 = *(const float2*)(x + (size_t)s1 * 128 + c);
        ax += v0.x * r0 + v1.x * r1;
        ay += v0.y * r0 + v1.y * r1;
    }
    if (i < end) {
        int s0 = ebuf[i];
        float r0 = rs_o[s0];
        float2 v0 = *(const float2*)(x + (size_t)s0 * 128 + c);
        ax += v0.x * r0;
        ay += v0.y * r0;
    }
    float2 vs = *(const float2*)(x + (size_t)d * 128 + c);
    float ro = rs_o[d], ri = rs_i[d];
    float2 o;
    o.x = (ax + vs.x * ro) * ri;
    o.y = (ay + vs.y * ro) * ri;
    *(float2*)(agg + (size_t)d * 128 + c) = o;
}

// ---------------------------------------------------------------------------
// next_h [8192][128] f32 -> Bt [128][8192] bf16 (transpose + convert)
// ---------------------------------------------------------------------------
__global__ void k_bt(const float* __restrict__ B, short* __restrict__ Bt) {
    __shared__ short T[32][40];     // [n_local][k_local], padded
    int kt = blockIdx.x & 255;      // k tile (32 wide)
    int nt = blockIdx.x >> 8;       // n tile (32 wide), 0..3
    int t = threadIdx.x;
    int r = t >> 3;                 // k_local 0..31
    int c4 = (t & 7) * 4;           // n_local 0,4..28
    float4 v = *(const float4*)(B + (size_t)(kt * 32 + r) * 128 + nt * 32 + c4);
    T[c4 + 0][r] = f2bf(v.x);
    T[c4 + 1][r] = f2bf(v.y);
    T[c4 + 2][r] = f2bf(v.z);
    T[c4 + 3][r] = f2bf(v.w);
    __syncthreads();
    int nl = t >> 3, ks = (t & 7) * 4;
    *(short4v*)(Bt + (size_t)(nt * 32 + nl) * 8192 + kt * 32 + ks) =
        *(const short4v*)(&T[nl][ks]);
}

// ---------------------------------------------------------------------------
// Big GEMM via MFMA: fused[16384][128] = curr_inc[16384][8192] @ next_h
// A converted f32->bf16 in-kernel (A read from HBM exactly once).
// Tile: 32 rows x 128 cols, BK=64, 256 threads (4 waves, wave = 32x32 slice).
// Verified gfx950 layouts: A-frag A[m=lane&15][k=(lane>>4)*8+j];
//                          C/D col=lane&15, row=(lane>>4)*4+reg.
// ---------------------------------------------------------------------------
__launch_bounds__(256, 2)
__global__ void k_mfma_gemm(const float* __restrict__ A, const short* __restrict__ Bt,
                            float* __restrict__ C) {
    __shared__ short As[32 * 72];    // [m][k], k-stride 72 (pad 8 -> 16B-aligned rows)
    __shared__ short Bs[128 * 72];   // [n][k]

    const int tid = threadIdx.x;
    const int lane = tid & 63;
    const int wv = tid >> 6;         // wave -> 32-col slice
    const int row0 = blockIdx.x * 32;

    // A staging: thread -> row ar, k-segment ak (8 floats -> 8 bf16)
    const int ar = tid >> 3;         // 0..31
    const int ak = (tid & 7) * 8;    // 0..56
    const float* Ap = A + (size_t)(row0 + ar) * Mm + ak;

    // B staging: thread -> n-row bn, k-segment bk (32 bf16 = 4 x short8)
    const int bn = tid >> 1;         // 0..127
    const int bk = (tid & 1) * 32;
    const short* Bp = Bt + (size_t)bn * Mm + bk;

    const int fm = lane & 15;        // fragment row/col
    const int fk = (lane >> 4) * 8;  // fragment k offset

    float4v acc[2][2] = {};

    for (int k0 = 0; k0 < Mm; k0 += 64) {
        float4 a0 = *(const float4*)(Ap + k0);
        float4 a1 = *(const float4*)(Ap + k0 + 4);
        short8v b0 = *(const short8v*)(Bp + k0);
        short8v b1 = *(const short8v*)(Bp + k0 + 8);
        short8v b2 = *(const short8v*)(Bp + k0 + 16);
        short8v b3 = *(const short8v*)(Bp + k0 + 24);
        __syncthreads();             // previous iter's LDS reads done
        short8v ap;
        ap[0] = f2bf(a0.x); ap[1] = f2bf(a0.y); ap[2] = f2bf(a0.z); ap[3] = f2bf(a0.w);
        ap[4] = f2bf(a1.x); ap[5] = f2bf(a1.y); ap[6] = f2bf(a1.z); ap[7] = f2bf(a1.w);
        *(short8v*)(&As[ar * 72 + ak]) = ap;
        *(short8v*)(&Bs[bn * 72 + bk +  0]) = b0;
        *(short8v*)(&Bs[bn * 72 + bk +  8]) = b1;
        *(short8v*)(&Bs[bn * 72 + bk + 16]) = b2;
        *(short8v*)(&Bs[bn * 72 + bk + 24]) = b3;
        __syncthreads();
#pragma unroll
        for (int ks = 0; ks < 2; ks++) {
            const int kk = ks * 32 + fk;
            short8v a0f = *(const short8v*)(&As[fm * 72 + kk]);
            short8v a1f = *(const short8v*)(&As[(16 + fm) * 72 + kk]);
            short8v b0f = *(const short8v*)(&Bs[(wv * 32 + fm) * 72 + kk]);
            short8v b1f = *(const short8v*)(&Bs[(wv * 32 + 16 + fm) * 72 + kk]);
            acc[0][0] = __builtin_amdgcn_mfma_f32_16x16x32_bf16(a0f, b0f, acc[0][0], 0, 0, 0);
            acc[0][1] = __builtin_amdgcn_mfma_f32_16x16x32_bf16(a0f, b1f, acc[0][1], 0, 0, 0);
            acc[1][0] = __builtin_amdgcn_mfma_f32_16x16x32_bf16(a1f, b0f, acc[1][0], 0, 0, 0);
            acc[1][1] = __builtin_amdgcn_mfma_f32_16x16x32_bf16(a1f, b1f, acc[1][1], 0, 0, 0);
        }
    }

    const int crow = (lane >> 4) * 4;
#pragma unroll
    for (int mt = 0; mt < 2; mt++)
#pragma unroll
        for (int nt = 0; nt < 2; nt++)
#pragma unroll
            for (int r = 0; r < 4; r++)
                C[(size_t)(row0 + mt * 16 + crow + r) * 128 + wv * 32 + nt * 16 + fm] =
                    acc[mt][nt][r];
}

// ---------------------------------------------------------------------------
// Small f32 GEMM (K=128): C[Nn,128] = A[Nn,K] @ B[K,128] with fused epilogue.
// mode 1: out = (acc + bias) * scale
// mode 2: out = ((acc + bias) * scale + prev) * 0.5
// ---------------------------------------------------------------------------
__launch_bounds__(256, 2)
__global__ void k_gemm(const float* __restrict__ A, const float* __restrict__ B,
                       float* __restrict__ C, int K,
                       const float* __restrict__ bias, const float* __restrict__ scale,
                       const float* __restrict__ prev, int mode) {
    __shared__ float As[32 * 36];
    __shared__ float Bs[32 * 128];

    const int tid = threadIdx.x;
    const int tx = tid & 31;
    const int ty = tid >> 5;
    const int c4 = tx * 4;
    const int r0 = ty * 4;
    const int row0 = blockIdx.x * 32;

    const int ar = tid >> 3;
    const int ak = (tid & 7) * 4;
    const float* Arow = A + (size_t)(row0 + ar) * K + ak;

    float acc[4][4] = {};

    for (int k0 = 0; k0 < K; k0 += 32) {
        float4 av = *(const float4*)(Arow + k0);
        float4 bv[4];
#pragma unroll
        for (int t = 0; t < 4; t++) {
            int idx = tid + t * 256;
            int br = idx >> 5, bc = (idx & 31) * 4;
            bv[t] = *(const float4*)(B + (size_t)(k0 + br) * 128 + bc);
        }
        __syncthreads();
        As[(ak + 0) * 36 + ar] = av.x;
        As[(ak + 1) * 36 + ar] = av.y;
        As[(ak + 2) * 36 + ar] = av.z;
        As[(ak + 3) * 36 + ar] = av.w;
#pragma unroll
        for (int t = 0; t < 4; t++) {
            int idx = tid + t * 256;
            int br = idx >> 5, bc = (idx & 31) * 4;
            *(float4*)(Bs + br * 128 + bc) = bv[t];
        }
        __syncthreads();
#pragma unroll
        for (int kk = 0; kk < 32; kk++) {
            float4 a4 = *(const float4*)(As + kk * 36 + r0);
            float4 b4 = *(const float4*)(Bs + kk * 128 + c4);
            float a[4] = {a4.x, a4.y, a4.z, a4.w};
            float b[4] = {b4.x, b4.y, b4.z, b4.w};
#pragma unroll
            for (int i = 0; i < 4; i++)
#pragma unroll
                for (int j = 0; j < 4; j++)
                    acc[i][j] = fmaf(a[i], b[j], acc[i][j]);
        }
    }

    float4 bi = *(const float4*)(bias + c4);
    float4 sc = *(const float4*)(scale + c4);
#pragma unroll
    for (int i = 0; i < 4; i++) {
        size_t o = (size_t)(row0 + r0 + i) * 128 + c4;
        float4 v = {acc[i][0], acc[i][1], acc[i][2], acc[i][3]};
        v.x = (v.x + bi.x) * sc.x;
        v.y = (v.y + bi.y) * sc.y;
        v.z = (v.z + bi.z) * sc.z;
        v.w = (v.w + bi.w) * sc.w;
        if (mode == 2) {
            float4 p = *(const float4*)(prev + o);
            v.x = (v.x + p.x) * 0.5f;
            v.y = (v.y + p.y) * 0.5f;
            v.z = (v.z + p.z) * 0.5f;
            v.w = (v.w + p.w) * 0.5f;
        }
        *(float4*)(C + o) = v;
    }
}

// ---------------------------------------------------------------------------
// LayerNorm (D=128) + affine + ReLU. One wave per row.
// ---------------------------------------------------------------------------
__global__ void k_ln_relu(const float* __restrict__ x, const float* __restrict__ gamma,
                          const float* __restrict__ beta, float* __restrict__ out) {
    int wave = threadIdx.x >> 6;
    int lane = threadIdx.x & 63;
    int row = blockIdx.x * 4 + wave;
    const float* xr = x + (size_t)row * 128;
    float2 v = *(const float2*)(xr + lane * 2);
    float s1 = v.x + v.y;
    float s2 = v.x * v.x + v.y * v.y;
#pragma unroll
    for (int m = 32; m >= 1; m >>= 1) {
        s1 += __shfl_xor(s1, m);
        s2 += __shfl_xor(s2, m);
    }
    float mu = s1 * (1.0f / 128.0f);
    float var = s2 * (1.0f / 128.0f) - mu * mu;
    float inv = rsqrtf(var + 1e-5f);
    float2 g = *(const float2*)(gamma + lane * 2);
    float2 b = *(const float2*)(beta + lane * 2);
    float2 o;
    o.x = fmaxf((v.x - mu) * inv * g.x + b.x, 0.0f);
    o.y = fmaxf((v.y - mu) * inv * g.y + b.y, 0.0f);
    *(float2*)(out + (size_t)row * 128 + lane * 2) = o;
}

// ---------------------------------------------------------------------------
extern "C" void kernel_launch(void* const* d_in, const int* in_sizes, int n_in,
                              void* d_out, int out_size, void* d_ws, size_t ws_size,
                              hipStream_t stream) {
    const float* curr_h    = (const float*)d_in[0];
    const float* next_h    = (const float*)d_in[1];
    const float* curr_inc  = (const float*)d_in[2];
    const float* Wc        = (const float*)d_in[3];
    const float* bc        = (const float*)d_in[4];
    const float* Wf        = (const float*)d_in[5];
    const float* bf        = (const float*)d_in[6];
    const float* conv_w    = (const float*)d_in[7];
    const float* topDown_w = (const float*)d_in[8];
    const float* gamma     = (const float*)d_in[9];
    const float* beta      = (const float*)d_in[10];
    const int*   esrc      = (const int*)d_in[11];
    const int*   edst      = (const int*)d_in[12];
    float* out = (float*)d_out;

    // workspace layout (~28.5 MB)
    char* w = (char*)d_ws;
    int*   cnt_out = (int*)w;    w += (size_t)Nn * 4;
    int*   cnt_in  = (int*)w;    w += (size_t)Nn * 4;
    int*   cursor  = (int*)w;    w += (size_t)Nn * 4;
    int*   row_st  = (int*)w;    w += (size_t)16388 * 4;
    int*   ebuf    = (int*)w;    w += (size_t)Ee * 4;
    float* rs_out  = (float*)w;  w += (size_t)Nn * 4;
    float* rs_in   = (float*)w;  w += (size_t)Nn * 4;
    short* Bt      = (short*)w;  w += (size_t)Dd * Mm * 2;
    float* fused   = (float*)w;  w += (size_t)Nn * Dd * 4;
    float* agg     = (float*)w;  w += (size_t)Nn * Dd * 4;
    float* path    = (float*)w;  w += (size_t)Nn * Dd * 4;

    // CSR + degrees
    k_zero_i<<<(3 * Nn + 255) / 256, 256, 0, stream>>>(cnt_out, 3 * Nn); // cnt_out,cnt_in,cursor contiguous
    k_deg_count<<<Ee / 256, 256, 0, stream>>>(esrc, edst, cnt_out, cnt_in);
    k_deg_fin<<<Nn / 256, 256, 0, stream>>>(cnt_out, cnt_in, rs_out, rs_in);
    k_scan<<<1, 1024, 0, stream>>>(cnt_in, row_st);
    k_fill<<<Ee / 256, 256, 0, stream>>>(esrc, edst, row_st, cursor, ebuf);

    // B^T bf16, then big MFMA GEMM: fused = curr_inc @ next_h
    k_bt<<<1024, 256, 0, stream>>>(next_h, Bt);
    k_mfma_gemm<<<Nn / 32, 256, 0, stream>>>(curr_inc, Bt, fused);

    // conv path
    k_agg<<<Nn / 4, 256, 0, stream>>>(curr_h, rs_out, rs_in, row_st, ebuf, agg);
    k_gemm<<<Nn / 32, 256, 0, stream>>>(agg, Wc, path, Dd, bc, conv_w, nullptr, 1);

    // top-down path + combine
    k_agg<<<Nn / 4, 256, 0, stream>>>(fused, rs_out, rs_in, row_st, ebuf, agg);
    k_gemm<<<Nn / 32, 256, 0, stream>>>(agg, Wf, path, Dd, bf, topDown_w, path, 2);

    // LayerNorm + ReLU
    k_ln_relu<<<Nn / 4, 256, 0, stream>>>(path, gamma, beta, out);
}